// Round 2
// baseline (104.870 us; speedup 1.0000x reference)
//
#include <hip/hip_runtime.h>

// NCuts loss: seg [8,4,224,224], padded_seg [8,4,232,232],
// weight [8,1,224,224,9,9], sum_weight [8,1,224,224] -> out[8] (fp32)

constexpr int NN  = 8;
constexpr int KK  = 4;
constexpr int HH  = 224;
constexpr int WW  = 224;
constexpr int PAD = 4;                   // RADIUS-1
constexpr int HP  = HH + 2 * PAD;        // 232
constexpr int WP  = WW + 2 * PAD;        // 232
constexpr int WINN = 9;
constexpr int NWIN = 81;
constexpr int PIX = HH * WW;             // 50176
constexpr int TPB = 256;
constexpr int PPT = 4;                   // pixels per thread (16B-aligned weight base)
constexpr int GRP = PIX / PPT;           // 12544 pixel-groups per image
constexpr int BPI = GRP / TPB;           // 49 blocks per image (exact)
constexpr int PLANE = HP * WP;           // 53824

__global__ __launch_bounds__(TPB) void ncuts_stage1(
    const float* __restrict__ seg, const float* __restrict__ pseg,
    const float* __restrict__ wgt, const float* __restrict__ swgt,
    float* __restrict__ part)
{
    const int blk = blockIdx.x;
    const int n   = blk / BPI;
    const int bi  = blk - n * BPI;
    const int tid = threadIdx.x;
    const int g   = bi * TPB + tid;          // pixel-group id, < GRP
    const int p0  = g * PPT;                 // first pixel of group (mult of 4)
    const int h   = p0 / WW;
    const int w   = p0 - h * WW;             // multiple of 4; group stays in one row

    // weight region for 4 pixels: 324 floats, base 16B-aligned
    const float4* wf = (const float4*)(wgt + ((size_t)n * PIX + p0) * NWIN);
    const float*  pb = pseg + (size_t)n * KK * PLANE + (size_t)h * WP + w;

    float acc[PPT][KK];
#pragma unroll
    for (int q = 0; q < PPT; ++q)
#pragma unroll
        for (int c = 0; c < KK; ++c) acc[q][c] = 0.f;

#pragma unroll
    for (int m = 0; m < WINN; ++m) {
        // pseg row union for the 4 pixels: cols w..w+11, per class
        float ps[KK][12];
#pragma unroll
        for (int c = 0; c < KK; ++c) {
            const float* pr = pb + (size_t)c * PLANE + m * WP;
            const float4 a = *(const float4*)(pr);
            const float4 b = *(const float4*)(pr + 4);
            const float4 d = *(const float4*)(pr + 8);
            ps[c][0] = a.x;  ps[c][1] = a.y;  ps[c][2]  = a.z;  ps[c][3]  = a.w;
            ps[c][4] = b.x;  ps[c][5] = b.y;  ps[c][6]  = b.z;  ps[c][7]  = b.w;
            ps[c][8] = d.x;  ps[c][9] = d.y;  ps[c][10] = d.z;  ps[c][11] = d.w;
        }
#pragma unroll
        for (int q = 0; q < PPT; ++q) {
            const int lin = NWIN * q + WINN * m;   // compile-time
            const int k0  = lin / 4;
            const int o   = lin % 4;
            const float4 w0 = wf[k0];
            const float4 w1 = wf[k0 + 1];
            const float4 w2 = wf[k0 + 2];
            float wv[12];
            wv[0] = w0.x; wv[1] = w0.y; wv[2]  = w0.z; wv[3]  = w0.w;
            wv[4] = w1.x; wv[5] = w1.y; wv[6]  = w1.z; wv[7]  = w1.w;
            wv[8] = w2.x; wv[9] = w2.y; wv[10] = w2.z; wv[11] = w2.w;
#pragma unroll
            for (int j = 0; j < WINN; ++j) {
                const float wvj = wv[o + j];
#pragma unroll
                for (int c = 0; c < KK; ++c)
                    acc[q][c] += ps[c][q + j] * wvj;
            }
        }
    }

    // seg / sum_weight for the 4 pixels (float4, aligned)
    const size_t sbase = (size_t)n * KK * PIX + p0;
    float vals[8];
#pragma unroll
    for (int c = 0; c < KK; ++c) {
        const float4 sg = *(const float4*)(seg + sbase + (size_t)c * PIX);
        const float s4[4] = { sg.x, sg.y, sg.z, sg.w };
        float A = 0.f;
#pragma unroll
        for (int q = 0; q < PPT; ++q) A += acc[q][c] * s4[q];
        vals[c] = A;
    }
    {
        const float4 sw = *(const float4*)(swgt + (size_t)n * PIX + p0);
        const float sw4[4] = { sw.x, sw.y, sw.z, sw.w };
#pragma unroll
        for (int c = 0; c < KK; ++c) {
            const float4 sg = *(const float4*)(seg + sbase + (size_t)c * PIX);
            const float s4[4] = { sg.x, sg.y, sg.z, sg.w };
            float V = 0.f;
#pragma unroll
            for (int q = 0; q < PPT; ++q) V += sw4[q] * s4[q];
            vals[4 + c] = V;
        }
    }

    __shared__ float lred[4][8];
    const int lane = tid & 63;
    const int wv_  = tid >> 6;
#pragma unroll
    for (int i = 0; i < 8; ++i) {
        float v = vals[i];
#pragma unroll
        for (int off = 32; off > 0; off >>= 1) v += __shfl_down(v, off, 64);
        if (lane == 0) lred[wv_][i] = v;
    }
    __syncthreads();
    if (tid < 8) {
        part[(size_t)blk * 8 + tid] =
            lred[0][tid] + lred[1][tid] + lred[2][tid] + lred[3][tid];
    }
}

__global__ __launch_bounds__(TPB) void ncuts_stage2(
    const float* __restrict__ part, float* __restrict__ out)
{
    const int n   = blockIdx.x;
    const int tid = threadIdx.x;

    float vals[8] = {0.f, 0.f, 0.f, 0.f, 0.f, 0.f, 0.f, 0.f};
    for (int b = tid; b < BPI; b += TPB) {
        const float* q = part + ((size_t)(n * BPI + b)) * 8;
#pragma unroll
        for (int i = 0; i < 8; ++i) vals[i] += q[i];
    }

    __shared__ float lred[4][8];
    const int lane = tid & 63;
    const int wv_  = tid >> 6;
#pragma unroll
    for (int i = 0; i < 8; ++i) {
        float v = vals[i];
#pragma unroll
        for (int off = 32; off > 0; off >>= 1) v += __shfl_down(v, off, 64);
        if (lane == 0) lred[wv_][i] = v;
    }
    __syncthreads();
    if (tid == 0) {
        float assoc = 0.f;
#pragma unroll
        for (int k = 0; k < 4; ++k) {
            const float A = lred[0][k] + lred[1][k] + lred[2][k] + lred[3][k];
            const float V = lred[0][4 + k] + lred[1][4 + k] + lred[2][4 + k] + lred[3][4 + k];
            assoc += A / V;
        }
        out[n] = 4.0f - assoc;
    }
}

extern "C" void kernel_launch(void* const* d_in, const int* in_sizes, int n_in,
                              void* d_out, int out_size, void* d_ws, size_t ws_size,
                              hipStream_t stream) {
    const float* seg  = (const float*)d_in[0];
    const float* pseg = (const float*)d_in[1];
    const float* wgt  = (const float*)d_in[2];
    const float* swgt = (const float*)d_in[3];
    float* out  = (float*)d_out;
    float* part = (float*)d_ws;   // 392 blocks * 8 floats

    ncuts_stage1<<<NN * BPI, TPB, 0, stream>>>(seg, pseg, wgt, swgt, part);
    ncuts_stage2<<<NN, TPB, 0, stream>>>(part, out);
}

// Round 3
// 64.004 us; speedup vs baseline: 1.6385x; 1.6385x over previous
//
#include <hip/hip_runtime.h>

// NCuts loss: seg [8,4,224,224], padded_seg [8,4,232,232],
// weight [8,1,224,224,9,9], sum_weight [8,1,224,224] -> out[8] (fp32)
//
// stage1: 64 pixels per block. Weight slab (64*81 floats, contiguous) staged
// into LDS fully coalesced; 81 taps split across the 4 waves (20/20/20/21)
// with compile-time tap indices; per-thread state = acc[4] only.

constexpr int NN  = 8;
constexpr int KK  = 4;
constexpr int HH  = 224;
constexpr int WW  = 224;
constexpr int PAD = 4;                   // RADIUS-1
constexpr int HP  = HH + 2 * PAD;        // 232
constexpr int WP  = WW + 2 * PAD;        // 232
constexpr int NWIN = 81;
constexpr int PIX = HH * WW;             // 50176
constexpr int TPB = 256;
constexpr int PPB = 64;                  // pixels per block
constexpr int BPI = PIX / PPB;           // 784 blocks per image
constexpr int PLANE = HP * WP;           // 53824

template<int T0, int T1>
__device__ inline void do_taps(const float* __restrict__ pb,
                               const float* __restrict__ lwp,
                               float acc[KK]) {
#pragma unroll
    for (int t = T0; t < T1; ++t) {
        const int m = t / 9;
        const int j = t - 9 * m;          // compile-time after unroll
        const float wv = lwp[t];          // ds_read, immediate offset
#pragma unroll
        for (int c = 0; c < KK; ++c)
            acc[c] += pb[(size_t)c * PLANE + m * WP + j] * wv;
    }
}

__global__ __launch_bounds__(TPB) void ncuts_stage1(
    const float* __restrict__ seg, const float* __restrict__ pseg,
    const float* __restrict__ wgt, const float* __restrict__ swgt,
    float* __restrict__ part)
{
    const int blk = blockIdx.x;
    const int n   = blk / BPI;
    const int bi  = blk - n * BPI;
    const int p0  = bi * PPB;
    const int tid = threadIdx.x;
    const int wv_ = tid >> 6;
    const int lane = tid & 63;

    __shared__ float lds_w[PPB * NWIN];   // 20736 B
    __shared__ float accB[PPB * 17];      // padded stride 17 -> conflict-free

    // ---- coalesced weight staging: 5184 floats = 1296 float4 ----
    {
        const float4* wsrc = (const float4*)(wgt + ((size_t)n * PIX + p0) * NWIN);
        float4* ldst = (float4*)lds_w;
        for (int i = tid; i < (PPB * NWIN) / 4; i += TPB) ldst[i] = wsrc[i];
    }
    __syncthreads();

    // ---- compute: wave wv_ handles its tap range for all 64 pixels ----
    const int p    = p0 + lane;
    const int h    = p / WW;
    const int wcol = p - h * WW;
    const float* pb  = pseg + (size_t)n * KK * PLANE + (size_t)h * WP + wcol;
    const float* lwp = lds_w + lane * NWIN;

    float acc[KK] = {0.f, 0.f, 0.f, 0.f};
    switch (wv_) {
        case 0:  do_taps<0, 20>(pb, lwp, acc); break;
        case 1:  do_taps<20, 40>(pb, lwp, acc); break;
        case 2:  do_taps<40, 60>(pb, lwp, acc); break;
        default: do_taps<60, 81>(pb, lwp, acc); break;
    }
#pragma unroll
    for (int c = 0; c < KK; ++c) accB[lane * 17 + wv_ * 4 + c] = acc[c];
    __syncthreads();

    // ---- epilogue: wave c owns class c; lanes = pixels ----
    const int c = wv_;
    const float r = accB[lane * 17 + c]     + accB[lane * 17 + 4 + c] +
                    accB[lane * 17 + 8 + c] + accB[lane * 17 + 12 + c];
    const float sv  = seg[(size_t)n * KK * PIX + (size_t)c * PIX + p];
    const float swv = swgt[(size_t)n * PIX + p];
    float A = r * sv;
    float V = swv * sv;
#pragma unroll
    for (int off = 32; off > 0; off >>= 1) {
        A += __shfl_down(A, off, 64);
        V += __shfl_down(V, off, 64);
    }
    if (lane == 0) {
        part[(size_t)blk * 8 + c]     = A;
        part[(size_t)blk * 8 + 4 + c] = V;
    }
}

__global__ __launch_bounds__(TPB) void ncuts_stage2(
    const float* __restrict__ part, float* __restrict__ out)
{
    const int n   = blockIdx.x;
    const int tid = threadIdx.x;

    float vals[8] = {0.f, 0.f, 0.f, 0.f, 0.f, 0.f, 0.f, 0.f};
    for (int b = tid; b < BPI; b += TPB) {
        const float* q = part + ((size_t)(n * BPI + b)) * 8;
#pragma unroll
        for (int i = 0; i < 8; ++i) vals[i] += q[i];
    }

    __shared__ float lred[4][8];
    const int lane = tid & 63;
    const int wv_  = tid >> 6;
#pragma unroll
    for (int i = 0; i < 8; ++i) {
        float v = vals[i];
#pragma unroll
        for (int off = 32; off > 0; off >>= 1) v += __shfl_down(v, off, 64);
        if (lane == 0) lred[wv_][i] = v;
    }
    __syncthreads();
    if (tid == 0) {
        float assoc = 0.f;
#pragma unroll
        for (int k = 0; k < 4; ++k) {
            const float A = lred[0][k] + lred[1][k] + lred[2][k] + lred[3][k];
            const float V = lred[0][4 + k] + lred[1][4 + k] + lred[2][4 + k] + lred[3][4 + k];
            assoc += A / V;
        }
        out[n] = 4.0f - assoc;
    }
}

extern "C" void kernel_launch(void* const* d_in, const int* in_sizes, int n_in,
                              void* d_out, int out_size, void* d_ws, size_t ws_size,
                              hipStream_t stream) {
    const float* seg  = (const float*)d_in[0];
    const float* pseg = (const float*)d_in[1];
    const float* wgt  = (const float*)d_in[2];
    const float* swgt = (const float*)d_in[3];
    float* out  = (float*)d_out;
    float* part = (float*)d_ws;   // 6272 blocks * 8 floats = 200704 B

    ncuts_stage1<<<NN * BPI, TPB, 0, stream>>>(seg, pseg, wgt, swgt, part);
    ncuts_stage2<<<NN, TPB, 0, stream>>>(part, out);
}

// Round 4
// 47.444 us; speedup vs baseline: 2.2104x; 1.3491x over previous
//
#include <hip/hip_runtime.h>

// NCuts loss: seg [8,4,224,224], padded_seg [8,4,232,232],
// weight [8,1,224,224,9,9], sum_weight [8,1,224,224] -> out[8] (fp32)
//
// stage1: 56 pixels per block (224/56=4 -> block never crosses an image row).
// Weight slab (56*81 floats) AND pseg tile (4 classes x 9 rows x 64 cols)
// staged into LDS fully coalesced; tap loop is pure LDS + FMA with
// compile-time immediate offsets. 81 taps split across 4 waves.

constexpr int NN  = 8;
constexpr int KK  = 4;
constexpr int HH  = 224;
constexpr int WW  = 224;
constexpr int PAD = 4;                   // RADIUS-1
constexpr int HP  = HH + 2 * PAD;        // 232
constexpr int WP  = WW + 2 * PAD;        // 232
constexpr int NWIN = 81;
constexpr int PIX = HH * WW;             // 50176
constexpr int TPB = 256;
constexpr int PPB = 56;                  // pixels per block, divides 224
constexpr int BPR = WW / PPB;            // 4 blocks per row
constexpr int BPI = BPR * HH;            // 896 blocks per image
constexpr int PLANE = HP * WP;           // 53824
constexpr int PSG_ROW = 64;              // 56 + 8 window cols, float4-aligned
constexpr int PSG_CLS = 9 * PSG_ROW;     // 576 floats per class tile

template<int T0, int T1>
__device__ inline void do_taps(const float* __restrict__ lwp,
                               const float* __restrict__ psl,
                               float acc[KK]) {
#pragma unroll
    for (int t = T0; t < T1; ++t) {
        const int m = t / 9;
        const int j = t - 9 * m;          // compile-time after unroll
        const float wv = lwp[t];          // ds_read_b32, immediate offset
#pragma unroll
        for (int c = 0; c < KK; ++c)
            acc[c] += psl[c * PSG_CLS + m * PSG_ROW + j] * wv;
    }
}

__global__ __launch_bounds__(TPB) void ncuts_stage1(
    const float* __restrict__ seg, const float* __restrict__ pseg,
    const float* __restrict__ wgt, const float* __restrict__ swgt,
    float* __restrict__ part)
{
    const int blk = blockIdx.x;
    const int n   = blk / BPI;
    const int bi  = blk - n * BPI;
    const int h0  = bi >> 2;                 // image row of this block
    const int w0  = (bi & 3) * PPB;          // first column
    const int p0  = h0 * WW + w0;
    const int tid = threadIdx.x;
    const int wv_ = tid >> 6;
    const int lane = tid & 63;

    __shared__ float lds_w[PPB * NWIN];          // 18144 B
    __shared__ float psg_lds[KK * PSG_CLS];      // 9216 B
    __shared__ float accB[PPB * 17];             // 3808 B, stride 17 -> no conflicts

    // ---- coalesced weight staging: 4536 floats = 1134 float4 ----
    {
        const float4* wsrc = (const float4*)(wgt + ((size_t)n * PIX + p0) * NWIN);
        float4* wdst = (float4*)lds_w;
        for (int i = tid; i < (PPB * NWIN) / 4; i += TPB) wdst[i] = wsrc[i];
    }
    // ---- coalesced pseg tile staging: 2304 floats = 576 float4 ----
    {
        const size_t nb = (size_t)n * KK * PLANE;
        float4* pdst = (float4*)psg_lds;
        for (int i = tid; i < (KK * PSG_CLS) / 4; i += TPB) {
            const int c  = i / (PSG_CLS / 4);
            const int r  = i - c * (PSG_CLS / 4);
            const int m  = r / (PSG_ROW / 4);
            const int c4 = r - m * (PSG_ROW / 4);
            pdst[i] = *(const float4*)(pseg + nb + (size_t)c * PLANE +
                                       (size_t)(h0 + m) * WP + w0 + c4 * 4);
        }
    }
    __syncthreads();

    // ---- compute: wave wv_ handles its tap range; lanes 0..55 = pixels ----
    float acc[KK] = {0.f, 0.f, 0.f, 0.f};
    if (lane < PPB) {
        const float* lwp = lds_w + lane * NWIN;
        const float* psl = psg_lds + lane;
        switch (wv_) {
            case 0:  do_taps<0, 20>(lwp, psl, acc); break;
            case 1:  do_taps<20, 40>(lwp, psl, acc); break;
            case 2:  do_taps<40, 60>(lwp, psl, acc); break;
            default: do_taps<60, 81>(lwp, psl, acc); break;
        }
#pragma unroll
        for (int c = 0; c < KK; ++c) accB[lane * 17 + wv_ * 4 + c] = acc[c];
    }
    __syncthreads();

    // ---- epilogue: wave c owns class c; lanes = pixels ----
    const int c = wv_;
    float A = 0.f, V = 0.f;
    if (lane < PPB) {
        const float r = accB[lane * 17 + c]     + accB[lane * 17 + 4 + c] +
                        accB[lane * 17 + 8 + c] + accB[lane * 17 + 12 + c];
        const float sv  = seg[(size_t)n * KK * PIX + (size_t)c * PIX + p0 + lane];
        const float swv = swgt[(size_t)n * PIX + p0 + lane];
        A = r * sv;
        V = swv * sv;
    }
#pragma unroll
    for (int off = 32; off > 0; off >>= 1) {
        A += __shfl_down(A, off, 64);
        V += __shfl_down(V, off, 64);
    }
    if (lane == 0) {
        part[(size_t)blk * 8 + c]     = A;
        part[(size_t)blk * 8 + 4 + c] = V;
    }
}

__global__ __launch_bounds__(TPB) void ncuts_stage2(
    const float* __restrict__ part, float* __restrict__ out)
{
    const int n   = blockIdx.x;
    const int tid = threadIdx.x;

    float vals[8] = {0.f, 0.f, 0.f, 0.f, 0.f, 0.f, 0.f, 0.f};
    for (int b = tid; b < BPI; b += TPB) {
        const float* q = part + ((size_t)(n * BPI + b)) * 8;
#pragma unroll
        for (int i = 0; i < 8; ++i) vals[i] += q[i];
    }

    __shared__ float lred[4][8];
    const int lane = tid & 63;
    const int wv_  = tid >> 6;
#pragma unroll
    for (int i = 0; i < 8; ++i) {
        float v = vals[i];
#pragma unroll
        for (int off = 32; off > 0; off >>= 1) v += __shfl_down(v, off, 64);
        if (lane == 0) lred[wv_][i] = v;
    }
    __syncthreads();
    if (tid == 0) {
        float assoc = 0.f;
#pragma unroll
        for (int k = 0; k < 4; ++k) {
            const float A = lred[0][k] + lred[1][k] + lred[2][k] + lred[3][k];
            const float V = lred[0][4 + k] + lred[1][4 + k] + lred[2][4 + k] + lred[3][4 + k];
            assoc += A / V;
        }
        out[n] = 4.0f - assoc;
    }
}

extern "C" void kernel_launch(void* const* d_in, const int* in_sizes, int n_in,
                              void* d_out, int out_size, void* d_ws, size_t ws_size,
                              hipStream_t stream) {
    const float* seg  = (const float*)d_in[0];
    const float* pseg = (const float*)d_in[1];
    const float* wgt  = (const float*)d_in[2];
    const float* swgt = (const float*)d_in[3];
    float* out  = (float*)d_out;
    float* part = (float*)d_ws;   // 7168 blocks * 8 floats = 229376 B

    ncuts_stage1<<<NN * BPI, TPB, 0, stream>>>(seg, pseg, wgt, swgt, part);
    ncuts_stage2<<<NN, TPB, 0, stream>>>(part, out);
}